// Round 12
// baseline (134.996 us; speedup 1.0000x reference)
//
#include <hip/hip_runtime.h>

// CRF NLL on MI355X — round 12: chunked scan, NO f16 merges.
// Each chunk's two half-products (2-way ILP in-wave, r10-proven) are stored
// SEPARATELY; all folding happens in the fp32 combine matvec (r9-class
// numerics: absmax was 0 with fp32-only folds, 1536/3072 with 8/16 f16
// merges). CCT=16 if ws fits (17.3 MB), else CCT=8 (8.65 MB, known fit).
// 2 kernels: chunks(+gold aux blocks) and combine (with row prefetch).

#define SS 512
#define TT 64
#define START_TAG 62
#define END_TAG 63
#define LOG2E_F 1.44269504088896340736f
#define LN2_F 0.69314718055994530942f
#define MSTR 72

typedef float v4f __attribute__((ext_vector_type(4)));
typedef _Float16 h4 __attribute__((ext_vector_type(4)));
typedef __fp16 c2 __attribute__((ext_vector_type(2)));
union H4u { h4 v; struct { c2 lo, hi; } p; };

// ---------------- per-step core (r9/r10-proven) ----------------
__device__ __forceinline__ void cstep(const h4 (&A)[4][4], h4 (&B)[4],
                                      float* __restrict__ emb, float& fq,
                                      const float* __restrict__ fcol, int tload,
                                      int q, int l, int& esum, int& esc) {
    v4f z = {0.f, 0.f, 0.f, 0.f};
    v4f D[4];
#pragma unroll
    for (int mt = 0; mt < 4; ++mt) {
        v4f a = __builtin_amdgcn_mfma_f32_16x16x16f16(A[mt][0], B[0], z, 0, 0, 0);
        a = __builtin_amdgcn_mfma_f32_16x16x16f16(A[mt][1], B[1], a, 0, 0, 0);
        v4f b = __builtin_amdgcn_mfma_f32_16x16x16f16(A[mt][2], B[2], z, 0, 0, 0);
        b = __builtin_amdgcn_mfma_f32_16x16x16f16(A[mt][3], B[3], b, 0, 0, 0);
        D[mt] = a + b;
    }
    v4f em[4];
#pragma unroll
    for (int mt = 0; mt < 4; ++mt) em[mt] = *(const v4f*)(emb + 16 * mt + 4 * q);
    emb[l] = __builtin_amdgcn_exp2f(fq * LOG2E_F);
    fq = fcol[(size_t)tload * TT];
    esum += esc;
    float scf = __uint_as_float((unsigned)(127 - esc) << 23);
    v4f qs[4];
#pragma unroll
    for (int mt = 0; mt < 4; ++mt) qs[mt] = D[mt] * (em[mt] * scf);
#pragma unroll
    for (int mt = 0; mt < 4; ++mt) {
        H4u u;
        u.p.lo = __builtin_amdgcn_cvt_pkrtz(qs[mt].x, qs[mt].y);
        u.p.hi = __builtin_amdgcn_cvt_pkrtz(qs[mt].z, qs[mt].w);
        B[mt] = u.v;
    }
    unsigned u0 = (unsigned)__builtin_amdgcn_readfirstlane((int)__float_as_uint(qs[0].x));
    esc = (int)((u0 >> 23) & 255u) - 127;
}

// ---------------- chunks kernel: 64*CCT chunk blocks + 64 gold aux blocks ----------------
template <int CCT>
__global__ __launch_bounds__(256, 1)
void crf_chunks(const float* __restrict__ feats, const float* __restrict__ trans,
                const int* __restrict__ mask, const int* __restrict__ tags,
                float* __restrict__ out, unsigned short* __restrict__ Pg,
                int* __restrict__ Eg, float* __restrict__ Gg) {
    constexpr int KCH_T = SS / CCT;
    constexpr int HALF = KCH_T / 2;
    constexpr int M = 2 * CCT;

    __shared__ __align__(16) float emA[4][2][TT];
    __shared__ __align__(16) float emB[4][2][TT];
    __shared__ __align__(16) _Float16 mld[TT * MSTR];
    __shared__ int li[4];
    __shared__ float gf[4];
    __shared__ int Lsh;

    const int blk = blockIdx.x;
    const int tid = threadIdx.x;

    if (blk >= 64 * CCT) {
        // ---- gold aux block: one chain per block (r10-prep structure) ----
        const int chain = blk - 64 * CCT;
        const int w = tid >> 6;
        int m = mask[chain * SS + tid] + mask[chain * SS + 256 + tid];
#pragma unroll
        for (int s_ = 1; s_ < 64; s_ <<= 1) m += __shfl_xor(m, s_, 64);
        if ((tid & 63) == 0) li[w] = m;
        __syncthreads();
        if (tid == 0) Lsh = li[0] + li[1] + li[2] + li[3];
        __syncthreads();
        const int Lc = Lsh;

        float g = 0.f;
#pragma unroll
        for (int rep = 0; rep < 2; ++rep) {
            int t = tid + rep * 256;
            if (t < Lc) {
                int cur = tags[chain * SS + t];
                int prev = (t == 0) ? START_TAG : tags[chain * SS + t - 1];
                g += feats[(size_t)chain * SS * TT + (size_t)t * TT + cur]
                   + trans[prev * TT + cur];
            }
        }
        if (tid == 0) g += trans[tags[chain * SS + Lc - 1] * TT + END_TAG];
#pragma unroll
        for (int s_ = 1; s_ < 64; s_ <<= 1) g += __shfl_xor(g, s_, 64);
        if ((tid & 63) == 0) gf[w] = g;
        __syncthreads();
        if (tid == 0) Gg[chain] = gf[0] + gf[1] + gf[2] + gf[3];
        if (chain == 0 && tid == 0) out[0] = 0.f;
        return;
    }

    const int chain = blk / CCT, c = blk % CCT;
    const int w = tid >> 6, l = tid & 63;
    const int n16 = l & 15, q = l >> 4;
    const int ncol = 16 * w + n16;

    // A = E^T stationary frags (per-block expf, r8/r9-proven prologue)
    h4 A[4][4];
#pragma unroll
    for (int mt = 0; mt < 4; ++mt)
#pragma unroll
        for (int ks = 0; ks < 4; ++ks) {
            h4 a;
#pragma unroll
            for (int e = 0; e < 4; ++e)
                a[e] = (_Float16)expf(trans[(16 * ks + 4 * q + e) * TT + 16 * mt + n16]);
            A[mt][ks] = a;
        }

    const int* mp = mask + chain * SS;
    int msum = 0;
#pragma unroll
    for (int k = 0; k < 8; ++k) msum += mp[k * 64 + l];
#pragma unroll
    for (int s_ = 1; s_ < 64; s_ <<= 1) msum += __shfl_xor(msum, s_, 64);
    const int L = msum;

    const int t0a = 1 + KCH_T * c;
    const int t0b = t0a + HALF;
    int nliveA = (L - 1) - KCH_T * c;
    nliveA = nliveA < 0 ? 0 : (nliveA > HALF ? HALF : nliveA);
    int nliveB = (L - 1) - KCH_T * c - HALF;
    nliveB = nliveB < 0 ? 0 : (nliveB > HALF ? HALF : nliveB);

    h4 BA[4], BB[4];
#pragma unroll
    for (int ks = 0; ks < 4; ++ks) {
        h4 b;
#pragma unroll
        for (int j = 0; j < 4; ++j)
            b[j] = (_Float16)((16 * ks + 4 * q + j == ncol) ? 1.f : 0.f);
        BA[ks] = b;
        BB[ks] = b;
    }

    const float* fcol = feats + (size_t)chain * SS * TT + l;
#define CLAMP_T(x) ((x) < SS ? (x) : SS - 1)
    emA[w][0][l] = __builtin_amdgcn_exp2f(fcol[(size_t)CLAMP_T(t0a) * TT] * LOG2E_F);
    emA[w][1][l] = __builtin_amdgcn_exp2f(fcol[(size_t)CLAMP_T(t0a + 1) * TT] * LOG2E_F);
    emB[w][0][l] = __builtin_amdgcn_exp2f(fcol[(size_t)CLAMP_T(t0b) * TT] * LOG2E_F);
    emB[w][1][l] = __builtin_amdgcn_exp2f(fcol[(size_t)CLAMP_T(t0b + 1) * TT] * LOG2E_F);
    float fqA0 = fcol[(size_t)CLAMP_T(t0a + 2) * TT];
    float fqA1 = fcol[(size_t)CLAMP_T(t0a + 3) * TT];
    float fqB0 = fcol[(size_t)CLAMP_T(t0b + 2) * TT];
    float fqB1 = fcol[(size_t)CLAMP_T(t0b + 3) * TT];

    int esumA = 0, escA = 0, esumB = 0, escB = 0;

    const int nB2 = nliveB & ~1;
    int s = 0;
    for (; s < nB2; s += 2) {
        cstep(A, BA, &emA[w][0][0], fqA0, fcol, CLAMP_T(t0a + s + 4), q, l, esumA, escA);
        cstep(A, BB, &emB[w][0][0], fqB0, fcol, CLAMP_T(t0b + s + 4), q, l, esumB, escB);
        cstep(A, BA, &emA[w][1][0], fqA1, fcol, CLAMP_T(t0a + s + 5), q, l, esumA, escA);
        cstep(A, BB, &emB[w][1][0], fqB1, fcol, CLAMP_T(t0b + s + 5), q, l, esumB, escB);
    }
    if (nliveB & 1)
        cstep(A, BB, &emB[w][0][0], fqB0, fcol, SS - 1, q, l, esumB, escB);
    for (; s + 1 < nliveA; s += 2) {
        cstep(A, BA, &emA[w][0][0], fqA0, fcol, CLAMP_T(t0a + s + 4), q, l, esumA, escA);
        cstep(A, BA, &emA[w][1][0], fqA1, fcol, CLAMP_T(t0a + s + 5), q, l, esumA, escA);
    }
    if (s < nliveA)
        cstep(A, BA, &emA[w][0][0], fqA0, fcol, SS - 1, q, l, esumA, escA);
#undef CLAMP_T

    // ---- epilogue: store BOTH half-products (no f16 merge) ----
    const size_t pbase = ((size_t)chain * M + 2 * c) * 4096;
    // Ha
#pragma unroll
    for (int ks = 0; ks < 4; ++ks)
#pragma unroll
        for (int j = 0; j < 4; ++j)
            mld[(16 * ks + 4 * q + j) * MSTR + ncol] = BA[ks][j];
    __syncthreads();
    {
        int r = tid >> 2, cb = tid & 3;
        const uint4* src = (const uint4*)(mld + r * MSTR + cb * 16);
        uint4* dst = (uint4*)(Pg + pbase + r * TT + cb * 16);
        dst[0] = src[0];
        dst[1] = src[1];
    }
    if (q == 0) Eg[(chain * M + 2 * c) * TT + ncol] = esumA;
    __syncthreads();
    // Hb
#pragma unroll
    for (int ks = 0; ks < 4; ++ks)
#pragma unroll
        for (int j = 0; j < 4; ++j)
            mld[(16 * ks + 4 * q + j) * MSTR + ncol] = BB[ks][j];
    __syncthreads();
    {
        int r = tid >> 2, cb = tid & 3;
        const uint4* src = (const uint4*)(mld + r * MSTR + cb * 16);
        uint4* dst = (uint4*)(Pg + pbase + 4096 + r * TT + cb * 16);
        dst[0] = src[0];
        dst[1] = src[1];
    }
    if (q == 0) Eg[(chain * M + 2 * c + 1) * TT + ncol] = esumB;
}

// ---------------- combine: fold 2*CCT matrices per chain in fp32 ----------------
template <int CCT>
__global__ __launch_bounds__(64, 1)
void crf_combine(const float* __restrict__ feats, const float* __restrict__ trans,
                 const unsigned short* __restrict__ Pg, const int* __restrict__ Eg,
                 const float* __restrict__ Gg, float* __restrict__ out) {
    constexpr int M = 2 * CCT;
    __shared__ __align__(16) float yl[TT];
    const int chain = blockIdx.x;
    const int j = threadIdx.x;

    float part0 = feats[(size_t)chain * SS * TT + j] + trans[START_TAG * TT + j];
    float M0 = part0;
#pragma unroll
    for (int m = 1; m < 64; m <<= 1) M0 = fmaxf(M0, __shfl_xor(M0, m, 64));
    float x = exp2f((part0 - M0) * LOG2E_F);
    int esumX = 0;

    // prefetch m=0 row + exponent
    uint4 rbuf[8];
    {
        const uint4* rp = (const uint4*)(Pg + ((size_t)chain * M) * 4096 + (size_t)j * TT);
#pragma unroll
        for (int i = 0; i < 8; ++i) rbuf[i] = rp[i];
    }
    int epre = Eg[(chain * M) * TT + j];

    for (int mm = 0; mm < M; ++mm) {
        int ecur = epre;
        uint4 rcur[8];
#pragma unroll
        for (int i = 0; i < 8; ++i) rcur[i] = rbuf[i];
        if (mm + 1 < M) {
            const uint4* rn = (const uint4*)(Pg + ((size_t)chain * M + mm + 1) * 4096 + (size_t)j * TT);
#pragma unroll
            for (int i = 0; i < 8; ++i) rbuf[i] = rn[i];
            epre = Eg[(chain * M + mm + 1) * TT + j];
        }

        int emax = ecur;
#pragma unroll
        for (int m = 1; m < 64; m <<= 1) emax = max(emax, __shfl_xor(emax, m, 64));
        yl[j] = ldexpf(x, ecur - emax);   // <= 0 shift: no overflow
        float yv[64];
        {
            const uint4* yq = (const uint4*)yl;
#pragma unroll
            for (int i = 0; i < 16; ++i) {
                union { uint4 u; float f[4]; } cv;
                cv.u = yq[i];
                yv[4 * i + 0] = cv.f[0]; yv[4 * i + 1] = cv.f[1];
                yv[4 * i + 2] = cv.f[2]; yv[4 * i + 3] = cv.f[3];
            }
        }
        float acc = 0.f;
#pragma unroll
        for (int i = 0; i < 8; ++i) {
            union { uint4 u; _Float16 h[8]; } pv;
            pv.u = rcur[i];
#pragma unroll
            for (int k2 = 0; k2 < 8; ++k2)
                acc = __builtin_fmaf((float)pv.h[k2], yv[8 * i + k2], acc);
        }
        float am = acc;
#pragma unroll
        for (int m = 1; m < 64; m <<= 1) am = fmaxf(am, __shfl_xor(am, m, 64));
        int e0 = (int)((__float_as_uint(am) >> 23) & 255u) - 127;
        x = ldexpf(acc, -e0);
        esumX += e0 + emax;
    }

    float val = x * expf(trans[j * TT + END_TAG]);
#pragma unroll
    for (int m = 1; m < 64; m <<= 1) val += __shfl_xor(val, m, 64);
    float fwd = logf(val) + (float)esumX * LN2_F + M0;
    if (j == 0) atomicAdd(out, fwd);

    if (chain == 0) {
        float gv = Gg[j];
#pragma unroll
        for (int m = 1; m < 64; m <<= 1) gv += __shfl_xor(gv, m, 64);
        if (j == 0) atomicAdd(out, -gv);
    }
}

extern "C" void kernel_launch(void* const* d_in, const int* in_sizes, int n_in,
                              void* d_out, int out_size, void* d_ws, size_t ws_size,
                              hipStream_t stream) {
    const float* feats = (const float*)d_in[0];
    const float* trans = (const float*)d_in[1];
    const int*   mask  = (const int*)d_in[2];
    const int*   tags  = (const int*)d_in[3];
    float* out = (float*)d_out;

    // ws layout (per CCT): P = 64*2*CCT*8192 B | Eg = 64*2*CCT*256 B | Gg = 256 B
    const size_t pb16 = 64ull * 32 * 8192, eb16 = 64ull * 32 * 256;
    const size_t need16 = pb16 + eb16 + 256;

    if (ws_size >= need16) {
        constexpr int C = 16;
        unsigned short* Pg = (unsigned short*)d_ws;
        int*   Eg = (int*)((char*)d_ws + pb16);
        float* Gg = (float*)((char*)d_ws + pb16 + eb16);
        crf_chunks<C><<<dim3(64 * C + 64), dim3(256), 0, stream>>>(feats, trans, mask, tags,
                                                                   out, Pg, Eg, Gg);
        crf_combine<C><<<dim3(64), dim3(64), 0, stream>>>(feats, trans, Pg, Eg, Gg, out);
    } else {
        constexpr int C = 8;
        const size_t pb8 = 64ull * 16 * 8192, eb8 = 64ull * 16 * 256;
        unsigned short* Pg = (unsigned short*)d_ws;
        int*   Eg = (int*)((char*)d_ws + pb8);
        float* Gg = (float*)((char*)d_ws + pb8 + eb8);
        crf_chunks<C><<<dim3(64 * C + 64), dim3(256), 0, stream>>>(feats, trans, mask, tags,
                                                                   out, Pg, Eg, Gg);
        crf_combine<C><<<dim3(64), dim3(64), 0, stream>>>(feats, trans, Pg, Eg, Gg, out);
    }
}

// Round 13
// 127.732 us; speedup vs baseline: 1.0569x; 1.0569x over previous
//
#include <hip/hip_runtime.h>

// CRF NLL on MI355X — round 13: chunked scan, 4-way ILP, staged emissions.
// CC=8 chunks of 64 steps; each chunk = FOUR 16-step quarter-products
// advanced interleaved in-wave (4 dependency chains in flight). All 32
// matrices per chain stored in f16; ALL folding in fp32 combine (r12-proven
// numerics, absmax 0). em = exp2(f) staged for all 64 steps in LDS up-front.
// Combine: slab-uniform emax (2 shuffles) + readfirstlane renorm + prefetch.

#define SS 512
#define TT 64
#define CCT 8
#define MM 32              // 4 * CCT matrices per chain
#define START_TAG 62
#define END_TAG 63
#define LOG2E_F 1.44269504088896340736f
#define LN2_F 0.69314718055994530942f
#define MSTR 72

typedef float v4f __attribute__((ext_vector_type(4)));
typedef _Float16 h4 __attribute__((ext_vector_type(4)));
typedef __fp16 c2 __attribute__((ext_vector_type(2)));
union H4u { h4 v; struct { c2 lo, hi; } p; };

// ---------------- per-step core: staged em, depth-4 MFMA ----------------
__device__ __forceinline__ void cstep(const h4 (&A)[4][4], h4 (&B)[4],
                                      const float* __restrict__ embase,
                                      int q, int& esum, int& esc) {
    v4f z = {0.f, 0.f, 0.f, 0.f};
    v4f D[4];
#pragma unroll
    for (int mt = 0; mt < 4; ++mt) {
        v4f a = __builtin_amdgcn_mfma_f32_16x16x16f16(A[mt][0], B[0], z, 0, 0, 0);
        a = __builtin_amdgcn_mfma_f32_16x16x16f16(A[mt][1], B[1], a, 0, 0, 0);
        a = __builtin_amdgcn_mfma_f32_16x16x16f16(A[mt][2], B[2], a, 0, 0, 0);
        a = __builtin_amdgcn_mfma_f32_16x16x16f16(A[mt][3], B[3], a, 0, 0, 0);
        D[mt] = a;
    }
    esum += esc;
    float scf = __uint_as_float((unsigned)(127 - esc) << 23);
    v4f qs[4];
#pragma unroll
    for (int mt = 0; mt < 4; ++mt) {
        v4f em = *(const v4f*)(embase + 16 * mt + 4 * q);
        qs[mt] = D[mt] * (em * scf);
    }
#pragma unroll
    for (int mt = 0; mt < 4; ++mt) {
        H4u u;
        u.p.lo = __builtin_amdgcn_cvt_pkrtz(qs[mt].x, qs[mt].y);
        u.p.hi = __builtin_amdgcn_cvt_pkrtz(qs[mt].z, qs[mt].w);
        B[mt] = u.v;
    }
    unsigned u0 = (unsigned)__builtin_amdgcn_readfirstlane((int)__float_as_uint(qs[0].x));
    esc = (int)((u0 >> 23) & 255u) - 127;
}

// ---------------- chunks kernel: 64*CCT chunk blocks + 64 gold blocks ----------------
__global__ __launch_bounds__(256, 1)
void crf_chunks(const float* __restrict__ feats, const float* __restrict__ trans,
                const int* __restrict__ mask, const int* __restrict__ tags,
                float* __restrict__ out, unsigned short* __restrict__ Pg,
                int* __restrict__ Eg, float* __restrict__ Gg) {
    __shared__ __align__(16) float smem[TT * TT];   // em_all[64 steps][64 rows]; aliased as mld in epilogue
    __shared__ int li[4];
    __shared__ float gf[4];
    __shared__ int Lsh;

    const int blk = blockIdx.x;
    const int tid = threadIdx.x;

    if (blk >= 64 * CCT) {
        // ---- gold aux block: one chain per block ----
        const int chain = blk - 64 * CCT;
        const int w = tid >> 6;
        int m = mask[chain * SS + tid] + mask[chain * SS + 256 + tid];
#pragma unroll
        for (int s_ = 1; s_ < 64; s_ <<= 1) m += __shfl_xor(m, s_, 64);
        if ((tid & 63) == 0) li[w] = m;
        __syncthreads();
        if (tid == 0) Lsh = li[0] + li[1] + li[2] + li[3];
        __syncthreads();
        const int Lc = Lsh;

        float g = 0.f;
#pragma unroll
        for (int rep = 0; rep < 2; ++rep) {
            int t = tid + rep * 256;
            if (t < Lc) {
                int cur = tags[chain * SS + t];
                int prev = (t == 0) ? START_TAG : tags[chain * SS + t - 1];
                g += feats[(size_t)chain * SS * TT + (size_t)t * TT + cur]
                   + trans[prev * TT + cur];
            }
        }
        if (tid == 0) g += trans[tags[chain * SS + Lc - 1] * TT + END_TAG];
#pragma unroll
        for (int s_ = 1; s_ < 64; s_ <<= 1) g += __shfl_xor(g, s_, 64);
        if ((tid & 63) == 0) gf[w] = g;
        __syncthreads();
        if (tid == 0) Gg[chain] = gf[0] + gf[1] + gf[2] + gf[3];
        if (chain == 0 && tid == 0) out[0] = 0.f;
        return;
    }

    const int chain = blk / CCT, c = blk % CCT;
    const int w = tid >> 6, l = tid & 63;
    const int n16 = l & 15, q = l >> 4;
    const int ncol = 16 * w + n16;
    const int t0 = 1 + 64 * c;

    // ---- A = E^T stationary frags ----
    h4 A[4][4];
#pragma unroll
    for (int mt = 0; mt < 4; ++mt)
#pragma unroll
        for (int ks = 0; ks < 4; ++ks) {
            h4 a;
#pragma unroll
            for (int e = 0; e < 4; ++e)
                a[e] = (_Float16)expf(trans[(16 * ks + 4 * q + e) * TT + 16 * mt + n16]);
            A[mt][ks] = a;
        }

    // ---- chain length L ----
    const int* mp = mask + chain * SS;
    int msum = 0;
#pragma unroll
    for (int k = 0; k < 8; ++k) msum += mp[k * 64 + l];
#pragma unroll
    for (int s_ = 1; s_ < 64; s_ <<= 1) msum += __shfl_xor(msum, s_, 64);
    const int L = msum;

    // ---- stage ALL 64 emission vectors for this chunk into LDS ----
    {
        const float* fb = feats + (size_t)chain * SS * TT;
#pragma unroll
        for (int r = 0; r < 16; ++r) {
            int idx = tid + r * 256;
            int si = idx >> 6, row = idx & 63;
            int t = t0 + si; t = t < SS ? t : SS - 1;
            smem[si * TT + row] =
                __builtin_amdgcn_exp2f(fb[(size_t)t * TT + row] * LOG2E_F);
        }
    }
    __syncthreads();

    // ---- quarter liveness (monotone: n0 >= n1 >= n2 >= n3) ----
    int base = (L - 1) - 64 * c;
    int n0 = base;          n0 = n0 < 0 ? 0 : (n0 > 16 ? 16 : n0);
    int n1 = base - 16;     n1 = n1 < 0 ? 0 : (n1 > 16 ? 16 : n1);
    int n2 = base - 32;     n2 = n2 < 0 ? 0 : (n2 > 16 ? 16 : n2);
    int n3 = base - 48;     n3 = n3 < 0 ? 0 : (n3 > 16 ? 16 : n3);

    // ---- identity inits for 4 quarter-products ----
    h4 B0[4], B1[4], B2[4], B3[4];
#pragma unroll
    for (int ks = 0; ks < 4; ++ks) {
        h4 b;
#pragma unroll
        for (int j = 0; j < 4; ++j)
            b[j] = (_Float16)((16 * ks + 4 * q + j == ncol) ? 1.f : 0.f);
        B0[ks] = b; B1[ks] = b; B2[ks] = b; B3[ks] = b;
    }

    int es0 = 0, ec0 = 0, es1 = 0, ec1 = 0, es2 = 0, ec2 = 0, es3 = 0, ec3 = 0;

    int s = 0;
    for (; s < n3; ++s) {
        cstep(A, B0, smem + (s)      * TT, q, es0, ec0);
        cstep(A, B1, smem + (16 + s) * TT, q, es1, ec1);
        cstep(A, B2, smem + (32 + s) * TT, q, es2, ec2);
        cstep(A, B3, smem + (48 + s) * TT, q, es3, ec3);
    }
    for (; s < n2; ++s) {
        cstep(A, B0, smem + (s)      * TT, q, es0, ec0);
        cstep(A, B1, smem + (16 + s) * TT, q, es1, ec1);
        cstep(A, B2, smem + (32 + s) * TT, q, es2, ec2);
    }
    for (; s < n1; ++s) {
        cstep(A, B0, smem + (s)      * TT, q, es0, ec0);
        cstep(A, B1, smem + (16 + s) * TT, q, es1, ec1);
    }
    for (; s < n0; ++s) {
        cstep(A, B0, smem + (s)      * TT, q, es0, ec0);
    }

    // ---- epilogue: store 4 quarter matrices (transpose via LDS, coalesced out) ----
    _Float16* mld = (_Float16*)smem;
    __syncthreads();   // done reading em_all
#define STORE_Q(Bq, esq, qi)                                                   \
    {                                                                          \
        _Pragma("unroll")                                                      \
        for (int ks = 0; ks < 4; ++ks)                                         \
            _Pragma("unroll")                                                  \
            for (int j = 0; j < 4; ++j)                                        \
                mld[(16 * ks + 4 * q + j) * MSTR + ncol] = Bq[ks][j];          \
        __syncthreads();                                                       \
        {                                                                      \
            const size_t pbase = ((size_t)chain * MM + 4 * c + (qi)) * 4096;   \
            int r = tid >> 2, cb = tid & 3;                                    \
            const uint4* src = (const uint4*)(mld + r * MSTR + cb * 16);       \
            uint4* dst = (uint4*)(Pg + pbase + r * TT + cb * 16);              \
            dst[0] = src[0];                                                   \
            dst[1] = src[1];                                                   \
        }                                                                      \
        if (q == 0) Eg[((size_t)chain * MM + 4 * c + (qi)) * TT + ncol] = esq; \
        __syncthreads();                                                       \
    }
    STORE_Q(B0, es0, 0)
    STORE_Q(B1, es1, 1)
    STORE_Q(B2, es2, 2)
    STORE_Q(B3, es3, 3)
#undef STORE_Q
}

// ---------------- combine: fold 32 matrices per chain in fp32 ----------------
__global__ __launch_bounds__(64, 1)
void crf_combine(const float* __restrict__ feats, const float* __restrict__ trans,
                 const unsigned short* __restrict__ Pg, const int* __restrict__ Eg,
                 const float* __restrict__ Gg, float* __restrict__ out) {
    __shared__ __align__(16) float yl[TT];
    const int chain = blockIdx.x;
    const int j = threadIdx.x;

    float part0 = feats[(size_t)chain * SS * TT + j] + trans[START_TAG * TT + j];
    float M0 = part0;
#pragma unroll
    for (int m = 1; m < 64; m <<= 1) M0 = fmaxf(M0, __shfl_xor(M0, m, 64));
    float x = exp2f((part0 - M0) * LOG2E_F);
    int esumX = 0;

    uint4 rbuf[8];
    {
        const uint4* rp = (const uint4*)(Pg + ((size_t)chain * MM) * 4096 + (size_t)j * TT);
#pragma unroll
        for (int i = 0; i < 8; ++i) rbuf[i] = rp[i];
    }
    int epre = Eg[((size_t)chain * MM) * TT + j];

    for (int mm = 0; mm < MM; ++mm) {
        int ecur = epre;
        uint4 rcur[8];
#pragma unroll
        for (int i = 0; i < 8; ++i) rcur[i] = rbuf[i];
        if (mm + 1 < MM) {
            const uint4* rn = (const uint4*)(Pg + ((size_t)chain * MM + mm + 1) * 4096 + (size_t)j * TT);
#pragma unroll
            for (int i = 0; i < 8; ++i) rbuf[i] = rn[i];
            epre = Eg[((size_t)chain * MM + mm + 1) * TT + j];
        }

        // emax: e is uniform within 16-lane slabs -> 2 shuffles suffice
        int emax = ecur;
        emax = max(emax, __shfl_xor(emax, 16, 64));
        emax = max(emax, __shfl_xor(emax, 32, 64));
        yl[j] = ldexpf(x, ecur - emax);   // <= 0 shift: exact, no overflow
        float yv[64];
        {
            const uint4* yq = (const uint4*)yl;
#pragma unroll
            for (int i = 0; i < 16; ++i) {
                union { uint4 u; float f[4]; } cv;
                cv.u = yq[i];
                yv[4 * i + 0] = cv.f[0]; yv[4 * i + 1] = cv.f[1];
                yv[4 * i + 2] = cv.f[2]; yv[4 * i + 3] = cv.f[3];
            }
        }
        float acc = 0.f;
#pragma unroll
        for (int i = 0; i < 8; ++i) {
            union { uint4 u; _Float16 h[8]; } pv;
            pv.u = rcur[i];
#pragma unroll
            for (int k2 = 0; k2 < 8; ++k2)
                acc = __builtin_fmaf((float)pv.h[k2], yv[8 * i + k2], acc);
        }
        // renorm via representative-lane exponent (exact pow2 bookkeeping)
        unsigned ub = (unsigned)__builtin_amdgcn_readfirstlane((int)__float_as_uint(acc));
        int e0 = (int)((ub >> 23) & 255u) - 127;
        x = ldexpf(acc, -e0);
        esumX += e0 + emax;
    }

    float val = x * expf(trans[j * TT + END_TAG]);
#pragma unroll
    for (int m = 1; m < 64; m <<= 1) val += __shfl_xor(val, m, 64);
    float fwd = logf(val) + (float)esumX * LN2_F + M0;
    if (j == 0) atomicAdd(out, fwd);

    if (chain == 0) {
        float gv = Gg[j];
#pragma unroll
        for (int m = 1; m < 64; m <<= 1) gv += __shfl_xor(gv, m, 64);
        if (j == 0) atomicAdd(out, -gv);
    }
}

extern "C" void kernel_launch(void* const* d_in, const int* in_sizes, int n_in,
                              void* d_out, int out_size, void* d_ws, size_t ws_size,
                              hipStream_t stream) {
    const float* feats = (const float*)d_in[0];
    const float* trans = (const float*)d_in[1];
    const int*   mask  = (const int*)d_in[2];
    const int*   tags  = (const int*)d_in[3];
    float* out = (float*)d_out;

    // ws layout: P = 64*32*8192 B (16.78 MB) | Eg = 64*32*256 B | Gg = 256 B
    // (17.3 MB total — proven to fit in r12's CC16 run)
    const size_t pb = 64ull * MM * 8192;
    const size_t eb = 64ull * MM * 256;
    unsigned short* Pg = (unsigned short*)d_ws;
    int*   Eg = (int*)((char*)d_ws + pb);
    float* Gg = (float*)((char*)d_ws + pb + eb);

    crf_chunks<<<dim3(64 * CCT + 64), dim3(256), 0, stream>>>(feats, trans, mask, tags,
                                                              out, Pg, Eg, Gg);
    crf_combine<<<dim3(64), dim3(64), 0, stream>>>(feats, trans, Pg, Eg, Gg, out);
}